// Round 4
// baseline (699.145 us; speedup 1.0000x reference)
//
#include <hip/hip_runtime.h>
#include <cstdint>
#include <cstddef>

#define B_ 8
#define S_ 1024
#define E_ 1024
#define H_ 16
#define D_ 64
#define M_ (B_*S_)

typedef _Float16 f16;
typedef __attribute__((ext_vector_type(8))) _Float16 f16x8;
typedef __attribute__((ext_vector_type(4))) _Float16 f16x4;
typedef __attribute__((ext_vector_type(2))) _Float16 f16x2;
typedef __attribute__((ext_vector_type(4))) float  f32x4;
typedef __attribute__((ext_vector_type(16))) float f32x16;
typedef __attribute__((ext_vector_type(4))) int    int4v;
typedef __attribute__((ext_vector_type(2))) int    int2v;

__device__ __forceinline__ f32x4 mfma16(f16x8 a, f16x8 b, f32x4 c) {
  return __builtin_amdgcn_mfma_f32_16x16x32_f16(a, b, c, 0, 0, 0);
}
__device__ __forceinline__ f32x16 mfma32(f16x8 a, f16x8 b, f32x16 c) {
  return __builtin_amdgcn_mfma_f32_32x32x16_f16(a, b, c, 0, 0, 0);
}
__device__ __forceinline__ void gll16(const f16* g, f16* l) {
  __builtin_amdgcn_global_load_lds(
      (const __attribute__((address_space(1))) void*)g,
      (__attribute__((address_space(3))) void*)l, 16, 0, 0);
}
__device__ __forceinline__ int pkrtz(float lo, float hi) {
  return __builtin_bit_cast(int, __builtin_amdgcn_cvt_pkrtz(lo, hi));
}

// ---------------------------------------------------------------------------
// X fp32 -> fp16 (single); memory-bound ~48MB
// ---------------------------------------------------------------------------
__global__ __launch_bounds__(256) void presplit_kernel(
    const float* __restrict__ X, f16* __restrict__ Xf) {
  size_t i = ((size_t)blockIdx.x * 256 + threadIdx.x) * 8;
  f32x4 v0 = *(const f32x4*)&X[i];
  f32x4 v1 = *(const f32x4*)&X[i + 4];
  f16x8 hv;
#pragma unroll
  for (int j = 0; j < 4; ++j) {
    hv[j] = (f16)v0[j];
    hv[j + 4] = (f16)v1[j];
  }
  *(f16x8*)&Xf[i] = hv;
}

// ---------------------------------------------------------------------------
// Transpose + split-convert weights -> fp16 hi/lo ([f][e] layout).
// W_Q is pre-scaled by log2(e) so attention scores are in log2 domain.
// z: 0=Q (scaled, hi/lo), 1=K (hi/lo), 2=V (hi only)
// ---------------------------------------------------------------------------
__global__ __launch_bounds__(512) void wt_conv3_kernel(
    const float* __restrict__ Wq, const float* __restrict__ Wk,
    const float* __restrict__ Wv, f16* __restrict__ qh, f16* __restrict__ ql,
    f16* __restrict__ kh, f16* __restrict__ kl, f16* __restrict__ vh) {
  const float* W = blockIdx.z == 0 ? Wq : (blockIdx.z == 1 ? Wk : Wv);
  f16* hi = blockIdx.z == 0 ? qh : (blockIdx.z == 1 ? kh : vh);
  f16* lo = blockIdx.z == 0 ? ql : (blockIdx.z == 1 ? kl : (f16*)nullptr);
  const float scl = blockIdx.z == 0 ? 1.4426950408889634f : 1.0f;
  __shared__ float t[64][65];
  const int f0 = blockIdx.x * 64, e0 = blockIdx.y * 64;
  const int tx = threadIdx.x, ty = threadIdx.y;
#pragma unroll
  for (int j = 0; j < 8; ++j)
    t[ty + 8 * j][tx] = W[(size_t)(e0 + ty + 8 * j) * E_ + f0 + tx];
  __syncthreads();
#pragma unroll
  for (int j = 0; j < 8; ++j) {
    float v = t[tx][ty + 8 * j] * scl;
    f16 hh = (f16)v;
    size_t idx = (size_t)(f0 + ty + 8 * j) * E_ + e0 + tx;
    hi[idx] = hh;
    if (lo) lo[idx] = (f16)(v - (float)hh);
  }
}

// ---------------------------------------------------------------------------
// Fused QKV projection GEMM, 2-term: O = X(f16) * (Wh + Wl).
// z=0: Q -> fp16 hi/lo [B,H,S,D] (log2e-scaled via W)
// z=1: K -> fp16 hi/lo [B,H,S,D]
// z=2: V -> fp16 single, transposed [B,H,D,S]
// BM=BN=128, BK=32, 4 waves; staged via global_load_lds w=16.
// ---------------------------------------------------------------------------
__global__ __launch_bounds__(256, 4) void gemm_qkv_kernel(
    const f16* __restrict__ Xf,
    const f16* __restrict__ Wqh, const f16* __restrict__ Wql,
    const f16* __restrict__ Wkh, const f16* __restrict__ Wkl,
    const f16* __restrict__ Wvh,
    f16* __restrict__ Qh, f16* __restrict__ Ql,
    f16* __restrict__ Kh, f16* __restrict__ Kl, f16* __restrict__ Vt) {
  __shared__ f16 sA[128][32], sBh[128][32], sBl[128][32];
  const int z = blockIdx.z;
  const f16* __restrict__ Bth = z == 0 ? Wqh : (z == 1 ? Wkh : Wvh);
  const f16* __restrict__ Btl = z == 0 ? Wql : Wkl;   // unused when z==2
  const int n0 = blockIdx.x * 128, m0 = blockIdx.y * 128;
  const int tid = threadIdx.x;
  const int lane = tid & 63, w = tid >> 6;
  const int wm = (w >> 1) * 64, wn = (w & 1) * 64;
  const int fr = lane & 15, fg = lane >> 4, ko = fg * 8;
  f32x4 acc[4][4] = {};
  for (int k0 = 0; k0 < E_; k0 += 32) {
#pragma unroll
    for (int i = 0; i < 2; ++i) {
      int ci = tid + i * 256;            // 512 chunks of 16B per 8KB tile
      int r = ci >> 2, c = (ci & 3) * 8;
      gll16(Xf  + (size_t)(m0 + r) * E_ + k0 + c, &sA[0][0] + ci * 8);
      gll16(Bth + (size_t)(n0 + r) * E_ + k0 + c, &sBh[0][0] + ci * 8);
      if (z < 2)
        gll16(Btl + (size_t)(n0 + r) * E_ + k0 + c, &sBl[0][0] + ci * 8);
    }
    __syncthreads();
    f16x8 ah[4];
#pragma unroll
    for (int mi = 0; mi < 4; ++mi)
      ah[mi] = *(const f16x8*)&sA[wm + mi * 16 + fr][ko];
    if (z < 2) {
#pragma unroll
      for (int ni = 0; ni < 4; ++ni) {
        f16x8 bh = *(const f16x8*)&sBh[wn + ni * 16 + fr][ko];
        f16x8 bl = *(const f16x8*)&sBl[wn + ni * 16 + fr][ko];
#pragma unroll
        for (int mi = 0; mi < 4; ++mi) {
          acc[mi][ni] = mfma16(ah[mi], bh, acc[mi][ni]);
          acc[mi][ni] = mfma16(ah[mi], bl, acc[mi][ni]);
        }
      }
    } else {
#pragma unroll
      for (int ni = 0; ni < 4; ++ni) {
        f16x8 bh = *(const f16x8*)&sBh[wn + ni * 16 + fr][ko];
#pragma unroll
        for (int mi = 0; mi < 4; ++mi)
          acc[mi][ni] = mfma16(ah[mi], bh, acc[mi][ni]);
      }
    }
    __syncthreads();
  }
  if (z < 2) {
    f16* Oh = z == 0 ? Qh : Kh;
    f16* Ol = z == 0 ? Ql : Kl;
#pragma unroll
    for (int mi = 0; mi < 4; ++mi)
#pragma unroll
      for (int ni = 0; ni < 4; ++ni)
#pragma unroll
        for (int r = 0; r < 4; ++r) {
          int row = m0 + wm + mi * 16 + fg * 4 + r;
          int col = n0 + wn + ni * 16 + fr;
          float v = acc[mi][ni][r];
          int bb = row >> 10, s = row & 1023;
          int hd = col >> 6, d = col & 63;
          size_t idx = ((size_t)(bb * H_ + hd) * S_ + s) * D_ + d;
          f16 hh = (f16)v;
          Oh[idx] = hh;
          Ol[idx] = (f16)(v - (float)hh);
        }
  } else {
#pragma unroll
    for (int mi = 0; mi < 4; ++mi)
#pragma unroll
      for (int ni = 0; ni < 4; ++ni) {
        int row = m0 + wm + mi * 16 + fg * 4;
        int col = n0 + wn + ni * 16 + fr;
        int bb = row >> 10, s = row & 1023;
        int hd = col >> 6, d = col & 63;
        f16x4 p;
#pragma unroll
        for (int r = 0; r < 4; ++r) p[r] = (f16)acc[mi][ni][r];
        *(f16x4*)&Vt[((size_t)(bb * H_ + hd) * D_ + d) * S_ + s] = p;
      }
  }
}

// ---------------------------------------------------------------------------
// Flash attention + ReLU.  Grid 1024 = 8 q-blocks x 128 (b,h); 4 waves x 32 q.
// Scores in log2 domain (W_Q pre-scaled); exp2 softmax; defer-max (THR=11);
// 3-term fp16 QK^T; in-register P (pkrtz+permlane); double-buffered staging.
// Same-head q-blocks map to the same XCD (bid&7 encodes head group).
// ---------------------------------------------------------------------------
__global__ __launch_bounds__(256, 3) void attn_kernel(
    const f16* __restrict__ Qh, const f16* __restrict__ Ql,
    const f16* __restrict__ Kh, const f16* __restrict__ Kl,
    const f16* __restrict__ Vt, float* __restrict__ out) {
  __shared__ f16 sKh[2][64][64], sKl[2][64][64], sV[2][64][64];
  const int bid = blockIdx.x;
  const int bh = (bid & 7) * 16 + ((bid >> 3) & 15);   // same head -> same XCD
  const int qb = bid >> 7;
  const int hd = bh & 15, bb = bh >> 4;
  const int tid = threadIdx.x;
  const int lane = tid & 63, w = tid >> 6;
  const int cq = lane & 31, h = lane >> 5;
  const size_t base = (size_t)bh * (S_ * D_);
  const f16* Qh_p = Qh + base;
  const f16* Ql_p = Ql + base;
  const f16* Kh_p = Kh + base;
  const f16* Kl_p = Kl + base;
  const f16* Vt_p = Vt + base;
  const int q0 = qb * 128 + w * 32;

  f16x8 qh_[4], ql_[4];
#pragma unroll
  for (int ks = 0; ks < 4; ++ks) {
    size_t off = (size_t)(q0 + cq) * D_ + ks * 16 + 8 * h;
    qh_[ks] = *(const f16x8*)&Qh_p[off];
    ql_[ks] = *(const f16x8*)&Ql_p[off];
  }

  float m_run = -1e30f, l_run = 0.f;
  f32x16 O[2] = {};

#define STAGE(buf, kb)                                                        \
  {                                                                           \
    _Pragma("unroll")                                                         \
    for (int half = 0; half < 2; ++half) {                                    \
      int ci = tid + half * 256;                                              \
      int row = ci >> 3, cl = ci & 7;                                         \
      int cs = cl ^ (row & 7);                                                \
      gll16(Kh_p + (size_t)((kb) + row) * D_ + cs * 8, &sKh[buf][0][0] + ci * 8); \
      gll16(Kl_p + (size_t)((kb) + row) * D_ + cs * 8, &sKl[buf][0][0] + ci * 8); \
      gll16(Vt_p + (size_t)row * S_ + (kb) + cs * 8, &sV[buf][0][0] + ci * 8);    \
    }                                                                         \
  }

  STAGE(0, 0);
  int cur = 0;
  for (int t = 0; t < 16; ++t) {
    __builtin_amdgcn_s_barrier();          // all waves done with buf cur^1
    if (t < 15) {
      STAGE(cur ^ 1, (t + 1) * 64);
      asm volatile("s_waitcnt vmcnt(6)" ::: "memory");
    } else {
      asm volatile("s_waitcnt vmcnt(0)" ::: "memory");
    }
    __builtin_amdgcn_sched_barrier(0);
    __builtin_amdgcn_s_barrier();          // staged chunk visible to all

    // ---- QK^T (swapped, 3-term): sc[f] = scores keys f*32.., query cq
    f32x16 sc[2] = {};
    __builtin_amdgcn_s_setprio(1);
#pragma unroll
    for (int f = 0; f < 2; ++f)
#pragma unroll
      for (int ks = 0; ks < 4; ++ks) {
        int row = f * 32 + cq;
        int cc = ((2 * ks + h) ^ (cq & 7)) * 8;
        f16x8 kh = *(const f16x8*)&sKh[cur][row][cc];
        f16x8 kl = *(const f16x8*)&sKl[cur][row][cc];
        sc[f] = mfma32(kh, qh_[ks], sc[f]);
        sc[f] = mfma32(kl, qh_[ks], sc[f]);
        sc[f] = mfma32(kh, ql_[ks], sc[f]);
      }
    __builtin_amdgcn_s_setprio(0);

    // ---- online softmax (log2 domain), defer-max THR=11
    float t8[8];
#pragma unroll
    for (int i = 0; i < 8; ++i)
      t8[i] = fmaxf(fmaxf(sc[0][i], sc[0][i + 8]),
                    fmaxf(sc[1][i], sc[1][i + 8]));
    float pmax = fmaxf(fmaxf(fmaxf(t8[0], t8[4]), fmaxf(t8[1], t8[5])),
                       fmaxf(fmaxf(t8[2], t8[6]), fmaxf(t8[3], t8[7])));
    pmax = fmaxf(pmax, __shfl_xor(pmax, 32));
    if (__any(pmax > m_run + 11.0f)) {
      float mn = fmaxf(m_run, pmax);
      float scale = __builtin_amdgcn_exp2f(m_run - mn);
      m_run = mn;
      l_run *= scale;
#pragma unroll
      for (int df = 0; df < 2; ++df)
#pragma unroll
        for (int i = 0; i < 16; ++i) O[df][i] *= scale;
    }
    float rs0 = 0.f, rs1 = 0.f, rs2 = 0.f, rs3 = 0.f;
#pragma unroll
    for (int f = 0; f < 2; ++f)
#pragma unroll
      for (int r = 0; r < 16; ++r) {
        float p = __builtin_amdgcn_exp2f(sc[f][r] - m_run);
        if ((r & 3) == 0) rs0 += p;
        else if ((r & 3) == 1) rs1 += p;
        else if ((r & 3) == 2) rs2 += p;
        else rs3 += p;
        sc[f][r] = p;
      }
    float rs = (rs0 + rs1) + (rs2 + rs3);
    rs += __shfl_xor(rs, 32);
    l_run += rs;

    // ---- PV (swapped): O[d][q] += V^T[d][k] * P[k][q], per-f interleaved
#pragma unroll
    for (int f = 0; f < 2; ++f) {
      f16x8 pfa, pfb;
#pragma unroll
      for (int ksl = 0; ksl < 2; ++ksl) {
        int b0 = 8 * ksl;
        int a1 = pkrtz(sc[f][b0 + 0], sc[f][b0 + 1]);
        int b1 = pkrtz(sc[f][b0 + 4], sc[f][b0 + 5]);
        int2v r1 = __builtin_amdgcn_permlane32_swap(a1, b1, false, false);
        int a2 = pkrtz(sc[f][b0 + 2], sc[f][b0 + 3]);
        int b2 = pkrtz(sc[f][b0 + 6], sc[f][b0 + 7]);
        int2v r2 = __builtin_amdgcn_permlane32_swap(a2, b2, false, false);
        int4v wd;
        wd[0] = r1[0]; wd[1] = r2[0]; wd[2] = r1[1]; wd[3] = r2[1];
        if (ksl == 0) pfa = __builtin_bit_cast(f16x8, wd);
        else          pfb = __builtin_bit_cast(f16x8, wd);
      }
      __builtin_amdgcn_s_setprio(1);
#pragma unroll
      for (int ksl = 0; ksl < 2; ++ksl) {
        int ks = 2 * f + ksl;
        int cc = ((2 * ks + h) ^ (cq & 7)) * 8;
#pragma unroll
        for (int df = 0; df < 2; ++df) {
          f16x8 vf = *(const f16x8*)&sV[cur][df * 32 + cq][cc];
          O[df] = mfma32(vf, ksl == 0 ? pfa : pfb, O[df]);
        }
      }
      __builtin_amdgcn_s_setprio(0);
    }
    cur ^= 1;
  }

  // ---- epilogue: relu(O/l) -> fp32 [B,S,E]
  float inv = 1.0f / l_run;
  int s = q0 + cq;
  float* orow = out + ((size_t)bb * S_ + s) * E_ + hd * 64;
#pragma unroll
  for (int df = 0; df < 2; ++df)
#pragma unroll
    for (int g = 0; g < 4; ++g) {
      f32x4 vv;
#pragma unroll
      for (int j = 0; j < 4; ++j)
        vv[j] = fmaxf(O[df][4 * g + j] * inv, 0.f);
      *(f32x4*)&orow[df * 32 + 8 * g + 4 * h] = vv;
    }
}

// ---------------------------------------------------------------------------
// Launcher. Workspace ~106 MB:
//  Wqh,Wql,Wkh,Wkl,Wvh 5x2MB @0; Xf @10M; Qh @26M; Ql @42M; Kh @58M;
//  Kl @74M; Vt @90M
// ---------------------------------------------------------------------------
extern "C" void kernel_launch(void* const* d_in, const int* in_sizes, int n_in,
                              void* d_out, int out_size, void* d_ws, size_t ws_size,
                              hipStream_t stream) {
  const float* X  = (const float*)d_in[0];
  const float* Wq = (const float*)d_in[1];
  const float* Wk = (const float*)d_in[2];
  const float* Wv = (const float*)d_in[3];
  float* out = (float*)d_out;
  char* ws = (char*)d_ws;

  const size_t WSZ = (size_t)E_ * E_ * sizeof(f16);   // 2 MB
  const size_t QSZ = (size_t)M_ * E_ * sizeof(f16);   // 16 MB
  f16* Wqh = (f16*)(ws);
  f16* Wql = (f16*)(ws + WSZ);
  f16* Wkh = (f16*)(ws + 2 * WSZ);
  f16* Wkl = (f16*)(ws + 3 * WSZ);
  f16* Wvh = (f16*)(ws + 4 * WSZ);
  char* p = ws + 5 * WSZ;
  f16* Xf = (f16*)(p);
  f16* Qh = (f16*)(p + QSZ);
  f16* Ql = (f16*)(p + 2 * QSZ);
  f16* Kh = (f16*)(p + 3 * QSZ);
  f16* Kl = (f16*)(p + 4 * QSZ);
  f16* Vt = (f16*)(p + 5 * QSZ);

  presplit_kernel<<<4096, 256, 0, stream>>>(X, Xf);
  wt_conv3_kernel<<<dim3(16, 16, 3), dim3(64, 8), 0, stream>>>(
      Wq, Wk, Wv, Wqh, Wql, Wkh, Wkl, Wvh);

  gemm_qkv_kernel<<<dim3(8, 64, 3), 256, 0, stream>>>(
      Xf, Wqh, Wql, Wkh, Wkl, Wvh, Qh, Ql, Kh, Kl, Vt);

  attn_kernel<<<1024, 256, 0, stream>>>(Qh, Ql, Kh, Kl, Vt, out);
}

// Round 5
// 195.720 us; speedup vs baseline: 3.5722x; 3.5722x over previous
//
#include <hip/hip_runtime.h>
#include <cstdint>
#include <cstddef>

#define B_ 8
#define S_ 1024
#define E_ 1024
#define H_ 16
#define D_ 64
#define M_ (B_*S_)

typedef _Float16 f16;
typedef __attribute__((ext_vector_type(8))) _Float16 f16x8;
typedef __attribute__((ext_vector_type(4))) _Float16 f16x4;
typedef __attribute__((ext_vector_type(4))) float  f32x4;
typedef __attribute__((ext_vector_type(16))) float f32x16;
typedef __attribute__((ext_vector_type(4))) int    int4v;
typedef __attribute__((ext_vector_type(2))) int    int2v;

__device__ __forceinline__ f32x4 mfma16(f16x8 a, f16x8 b, f32x4 c) {
  return __builtin_amdgcn_mfma_f32_16x16x32_f16(a, b, c, 0, 0, 0);
}
__device__ __forceinline__ f32x16 mfma32(f16x8 a, f16x8 b, f32x16 c) {
  return __builtin_amdgcn_mfma_f32_32x32x16_f16(a, b, c, 0, 0, 0);
}
__device__ __forceinline__ void gll16(const f16* g, f16* l) {
  __builtin_amdgcn_global_load_lds(
      (const __attribute__((address_space(1))) void*)g,
      (__attribute__((address_space(3))) void*)l, 16, 0, 0);
}
__device__ __forceinline__ int pkrtz(float lo, float hi) {
  return __builtin_bit_cast(int, __builtin_amdgcn_cvt_pkrtz(lo, hi));
}

// ---------------------------------------------------------------------------
// X fp32 -> fp16 (single); memory-bound ~48MB
// ---------------------------------------------------------------------------
__global__ __launch_bounds__(256) void presplit_kernel(
    const float* __restrict__ X, f16* __restrict__ Xf) {
  size_t i = ((size_t)blockIdx.x * 256 + threadIdx.x) * 8;
  f32x4 v0 = *(const f32x4*)&X[i];
  f32x4 v1 = *(const f32x4*)&X[i + 4];
  f16x8 hv;
#pragma unroll
  for (int j = 0; j < 4; ++j) {
    hv[j] = (f16)v0[j];
    hv[j + 4] = (f16)v1[j];
  }
  *(f16x8*)&Xf[i] = hv;
}

// ---------------------------------------------------------------------------
// Transpose + split-convert weights -> fp16 hi/lo ([f][e] layout).
// W_Q is pre-scaled by log2(e) so attention scores are in log2 domain.
// z: 0=Q (scaled, hi/lo), 1=K (hi/lo), 2=V (hi only)
// ---------------------------------------------------------------------------
__global__ __launch_bounds__(512) void wt_conv3_kernel(
    const float* __restrict__ Wq, const float* __restrict__ Wk,
    const float* __restrict__ Wv, f16* __restrict__ qh, f16* __restrict__ ql,
    f16* __restrict__ kh, f16* __restrict__ kl, f16* __restrict__ vh) {
  const float* W = blockIdx.z == 0 ? Wq : (blockIdx.z == 1 ? Wk : Wv);
  f16* hi = blockIdx.z == 0 ? qh : (blockIdx.z == 1 ? kh : vh);
  f16* lo = blockIdx.z == 0 ? ql : (blockIdx.z == 1 ? kl : (f16*)nullptr);
  const float scl = blockIdx.z == 0 ? 1.4426950408889634f : 1.0f;
  __shared__ float t[64][65];
  const int f0 = blockIdx.x * 64, e0 = blockIdx.y * 64;
  const int tx = threadIdx.x, ty = threadIdx.y;
#pragma unroll
  for (int j = 0; j < 8; ++j)
    t[ty + 8 * j][tx] = W[(size_t)(e0 + ty + 8 * j) * E_ + f0 + tx];
  __syncthreads();
#pragma unroll
  for (int j = 0; j < 8; ++j) {
    float v = t[tx][ty + 8 * j] * scl;
    f16 hh = (f16)v;
    size_t idx = (size_t)(f0 + ty + 8 * j) * E_ + e0 + tx;
    hi[idx] = hh;
    if (lo) lo[idx] = (f16)(v - (float)hh);
  }
}

// ---------------------------------------------------------------------------
// Fused QKV projection GEMM, 2-term: O = X(f16) * (Wh + Wl).
// z=0: Q -> fp16 hi/lo [B,H,S,D] (log2e-scaled via W)
// z=1: K -> fp16 hi/lo [B,H,S,D]
// z=2: V -> fp16 single, transposed [B,H,D,S]
// BM=BN=128, BK=64, 4 waves.  LDS tiles are XOR-swizzled on 16B chunks
// (chunk' = chunk ^ (row&7)); staging keeps LDS linear and pre-swizzles the
// GLOBAL source column (rule 21), fragment reads apply the same XOR.
// NOTE: plain __launch_bounds__(256) -- a min-waves clamp here caps VGPR at 64
// and spills the 64-reg accumulator to scratch (round-4 regression: 1GB fetch).
// ---------------------------------------------------------------------------
__global__ __launch_bounds__(256) void gemm_qkv_kernel(
    const f16* __restrict__ Xf,
    const f16* __restrict__ Wqh, const f16* __restrict__ Wql,
    const f16* __restrict__ Wkh, const f16* __restrict__ Wkl,
    const f16* __restrict__ Wvh,
    f16* __restrict__ Qh, f16* __restrict__ Ql,
    f16* __restrict__ Kh, f16* __restrict__ Kl, f16* __restrict__ Vt) {
  __shared__ f16 sA[128][64], sBh[128][64], sBl[128][64];   // 48 KB
  const int z = blockIdx.z;
  const f16* __restrict__ Bth = z == 0 ? Wqh : (z == 1 ? Wkh : Wvh);
  const f16* __restrict__ Btl = z == 0 ? Wql : Wkl;   // unused when z==2
  const int n0 = blockIdx.x * 128, m0 = blockIdx.y * 128;
  const int tid = threadIdx.x;
  const int lane = tid & 63, w = tid >> 6;
  const int wm = (w >> 1) * 64, wn = (w & 1) * 64;
  const int fr = lane & 15, fg = lane >> 4;
  f32x4 acc[4][4] = {};
  for (int k0 = 0; k0 < E_; k0 += 64) {
    // stage 16KB per stream: 1024 chunks of 16B, 4 per thread
#pragma unroll
    for (int i = 0; i < 4; ++i) {
      int ci = tid + i * 256;
      int r = ci >> 3, cl = ci & 7;
      int cs = (cl ^ (r & 7)) * 8;       // pre-swizzled global source column
      gll16(Xf  + (size_t)(m0 + r) * E_ + k0 + cs, &sA[0][0] + ci * 8);
      gll16(Bth + (size_t)(n0 + r) * E_ + k0 + cs, &sBh[0][0] + ci * 8);
      if (z < 2)
        gll16(Btl + (size_t)(n0 + r) * E_ + k0 + cs, &sBl[0][0] + ci * 8);
    }
    __syncthreads();   // drains vmcnt -> staged tile visible to all
#pragma unroll
    for (int kh2 = 0; kh2 < 2; ++kh2) {   // two 32-wide MFMA K-steps
      f16x8 ah[4];
#pragma unroll
      for (int mi = 0; mi < 4; ++mi) {
        int rA = wm + mi * 16 + fr;
        ah[mi] = *(const f16x8*)&sA[rA][(((kh2 * 4 + fg) ^ (rA & 7))) * 8];
      }
      if (z < 2) {
#pragma unroll
        for (int ni = 0; ni < 4; ++ni) {
          int rB = wn + ni * 16 + fr;
          int cc = (((kh2 * 4 + fg) ^ (rB & 7))) * 8;
          f16x8 bh = *(const f16x8*)&sBh[rB][cc];
          f16x8 bl = *(const f16x8*)&sBl[rB][cc];
#pragma unroll
          for (int mi = 0; mi < 4; ++mi) {
            acc[mi][ni] = mfma16(ah[mi], bh, acc[mi][ni]);
            acc[mi][ni] = mfma16(ah[mi], bl, acc[mi][ni]);
          }
        }
      } else {
#pragma unroll
        for (int ni = 0; ni < 4; ++ni) {
          int rB = wn + ni * 16 + fr;
          int cc = (((kh2 * 4 + fg) ^ (rB & 7))) * 8;
          f16x8 bh = *(const f16x8*)&sBh[rB][cc];
#pragma unroll
          for (int mi = 0; mi < 4; ++mi)
            acc[mi][ni] = mfma16(ah[mi], bh, acc[mi][ni]);
        }
      }
    }
    __syncthreads();   // compute done before next stage overwrites
  }
  if (z < 2) {
    f16* Oh = z == 0 ? Qh : Kh;
    f16* Ol = z == 0 ? Ql : Kl;
#pragma unroll
    for (int mi = 0; mi < 4; ++mi)
#pragma unroll
      for (int ni = 0; ni < 4; ++ni)
#pragma unroll
        for (int r = 0; r < 4; ++r) {
          int row = m0 + wm + mi * 16 + (lane >> 4) * 4 + r;
          int col = n0 + wn + ni * 16 + fr;
          float v = acc[mi][ni][r];
          int bb = row >> 10, s = row & 1023;
          int hd = col >> 6, d = col & 63;
          size_t idx = ((size_t)(bb * H_ + hd) * S_ + s) * D_ + d;
          f16 hh = (f16)v;
          Oh[idx] = hh;
          Ol[idx] = (f16)(v - (float)hh);
        }
  } else {
#pragma unroll
    for (int mi = 0; mi < 4; ++mi)
#pragma unroll
      for (int ni = 0; ni < 4; ++ni) {
        int row = m0 + wm + mi * 16 + (lane >> 4) * 4;
        int col = n0 + wn + ni * 16 + fr;
        int bb = row >> 10, s = row & 1023;
        int hd = col >> 6, d = col & 63;
        f16x4 p;
#pragma unroll
        for (int r = 0; r < 4; ++r) p[r] = (f16)acc[mi][ni][r];
        *(f16x4*)&Vt[((size_t)(bb * H_ + hd) * D_ + d) * S_ + s] = p;
      }
  }
}

// ---------------------------------------------------------------------------
// Flash attention + ReLU.  Grid 1024 = 8 q-blocks x 128 (b,h); 4 waves x 32 q.
// Scores in log2 domain (W_Q pre-scaled); exp2 softmax; defer-max (THR=11);
// 3-term fp16 QK^T; in-register P (pkrtz+permlane); double-buffered staging.
// (unchanged from round 4)
// ---------------------------------------------------------------------------
__global__ __launch_bounds__(256, 3) void attn_kernel(
    const f16* __restrict__ Qh, const f16* __restrict__ Ql,
    const f16* __restrict__ Kh, const f16* __restrict__ Kl,
    const f16* __restrict__ Vt, float* __restrict__ out) {
  __shared__ f16 sKh[2][64][64], sKl[2][64][64], sV[2][64][64];
  const int bid = blockIdx.x;
  const int bh = (bid & 7) * 16 + ((bid >> 3) & 15);   // same head -> same XCD
  const int qb = bid >> 7;
  const int hd = bh & 15, bb = bh >> 4;
  const int tid = threadIdx.x;
  const int lane = tid & 63, w = tid >> 6;
  const int cq = lane & 31, h = lane >> 5;
  const size_t base = (size_t)bh * (S_ * D_);
  const f16* Qh_p = Qh + base;
  const f16* Ql_p = Ql + base;
  const f16* Kh_p = Kh + base;
  const f16* Kl_p = Kl + base;
  const f16* Vt_p = Vt + base;
  const int q0 = qb * 128 + w * 32;

  f16x8 qh_[4], ql_[4];
#pragma unroll
  for (int ks = 0; ks < 4; ++ks) {
    size_t off = (size_t)(q0 + cq) * D_ + ks * 16 + 8 * h;
    qh_[ks] = *(const f16x8*)&Qh_p[off];
    ql_[ks] = *(const f16x8*)&Ql_p[off];
  }

  float m_run = -1e30f, l_run = 0.f;
  f32x16 O[2] = {};

#define STAGE(buf, kb)                                                        \
  {                                                                           \
    _Pragma("unroll")                                                         \
    for (int half = 0; half < 2; ++half) {                                    \
      int ci = tid + half * 256;                                              \
      int row = ci >> 3, cl = ci & 7;                                         \
      int cs = cl ^ (row & 7);                                                \
      gll16(Kh_p + (size_t)((kb) + row) * D_ + cs * 8, &sKh[buf][0][0] + ci * 8); \
      gll16(Kl_p + (size_t)((kb) + row) * D_ + cs * 8, &sKl[buf][0][0] + ci * 8); \
      gll16(Vt_p + (size_t)row * S_ + (kb) + cs * 8, &sV[buf][0][0] + ci * 8);    \
    }                                                                         \
  }

  STAGE(0, 0);
  int cur = 0;
  for (int t = 0; t < 16; ++t) {
    __builtin_amdgcn_s_barrier();          // all waves done with buf cur^1
    if (t < 15) {
      STAGE(cur ^ 1, (t + 1) * 64);
      asm volatile("s_waitcnt vmcnt(6)" ::: "memory");
    } else {
      asm volatile("s_waitcnt vmcnt(0)" ::: "memory");
    }
    __builtin_amdgcn_sched_barrier(0);
    __builtin_amdgcn_s_barrier();          // staged chunk visible to all

    // ---- QK^T (swapped, 3-term): sc[f] = scores keys f*32.., query cq
    f32x16 sc[2] = {};
    __builtin_amdgcn_s_setprio(1);
#pragma unroll
    for (int f = 0; f < 2; ++f)
#pragma unroll
      for (int ks = 0; ks < 4; ++ks) {
        int row = f * 32 + cq;
        int cc = ((2 * ks + h) ^ (cq & 7)) * 8;
        f16x8 kh = *(const f16x8*)&sKh[cur][row][cc];
        f16x8 kl = *(const f16x8*)&sKl[cur][row][cc];
        sc[f] = mfma32(kh, qh_[ks], sc[f]);
        sc[f] = mfma32(kl, qh_[ks], sc[f]);
        sc[f] = mfma32(kh, ql_[ks], sc[f]);
      }
    __builtin_amdgcn_s_setprio(0);

    // ---- online softmax (log2 domain), defer-max THR=11
    float t8[8];
#pragma unroll
    for (int i = 0; i < 8; ++i)
      t8[i] = fmaxf(fmaxf(sc[0][i], sc[0][i + 8]),
                    fmaxf(sc[1][i], sc[1][i + 8]));
    float pmax = fmaxf(fmaxf(fmaxf(t8[0], t8[4]), fmaxf(t8[1], t8[5])),
                       fmaxf(fmaxf(t8[2], t8[6]), fmaxf(t8[3], t8[7])));
    pmax = fmaxf(pmax, __shfl_xor(pmax, 32));
    if (__any(pmax > m_run + 11.0f)) {
      float mn = fmaxf(m_run, pmax);
      float scale = __builtin_amdgcn_exp2f(m_run - mn);
      m_run = mn;
      l_run *= scale;
#pragma unroll
      for (int df = 0; df < 2; ++df)
#pragma unroll
        for (int i = 0; i < 16; ++i) O[df][i] *= scale;
    }
    float rs0 = 0.f, rs1 = 0.f, rs2 = 0.f, rs3 = 0.f;
#pragma unroll
    for (int f = 0; f < 2; ++f)
#pragma unroll
      for (int r = 0; r < 16; ++r) {
        float p = __builtin_amdgcn_exp2f(sc[f][r] - m_run);
        if ((r & 3) == 0) rs0 += p;
        else if ((r & 3) == 1) rs1 += p;
        else if ((r & 3) == 2) rs2 += p;
        else rs3 += p;
        sc[f][r] = p;
      }
    float rs = (rs0 + rs1) + (rs2 + rs3);
    rs += __shfl_xor(rs, 32);
    l_run += rs;

    // ---- PV (swapped): O[d][q] += V^T[d][k] * P[k][q], per-f interleaved
#pragma unroll
    for (int f = 0; f < 2; ++f) {
      f16x8 pfa, pfb;
#pragma unroll
      for (int ksl = 0; ksl < 2; ++ksl) {
        int b0 = 8 * ksl;
        int a1 = pkrtz(sc[f][b0 + 0], sc[f][b0 + 1]);
        int b1 = pkrtz(sc[f][b0 + 4], sc[f][b0 + 5]);
        int2v r1 = __builtin_amdgcn_permlane32_swap(a1, b1, false, false);
        int a2 = pkrtz(sc[f][b0 + 2], sc[f][b0 + 3]);
        int b2 = pkrtz(sc[f][b0 + 6], sc[f][b0 + 7]);
        int2v r2 = __builtin_amdgcn_permlane32_swap(a2, b2, false, false);
        int4v wd;
        wd[0] = r1[0]; wd[1] = r2[0]; wd[2] = r1[1]; wd[3] = r2[1];
        if (ksl == 0) pfa = __builtin_bit_cast(f16x8, wd);
        else          pfb = __builtin_bit_cast(f16x8, wd);
      }
      __builtin_amdgcn_s_setprio(1);
#pragma unroll
      for (int ksl = 0; ksl < 2; ++ksl) {
        int ks = 2 * f + ksl;
        int cc = ((2 * ks + h) ^ (cq & 7)) * 8;
#pragma unroll
        for (int df = 0; df < 2; ++df) {
          f16x8 vf = *(const f16x8*)&sV[cur][df * 32 + cq][cc];
          O[df] = mfma32(vf, ksl == 0 ? pfa : pfb, O[df]);
        }
      }
      __builtin_amdgcn_s_setprio(0);
    }
    cur ^= 1;
  }

  // ---- epilogue: relu(O/l) -> fp32 [B,S,E]
  float inv = 1.0f / l_run;
  int s = q0 + cq;
  float* orow = out + ((size_t)bb * S_ + s) * E_ + hd * 64;
#pragma unroll
  for (int df = 0; df < 2; ++df)
#pragma unroll
    for (int g = 0; g < 4; ++g) {
      f32x4 vv;
#pragma unroll
      for (int j = 0; j < 4; ++j)
        vv[j] = fmaxf(O[df][4 * g + j] * inv, 0.f);
      *(f32x4*)&orow[df * 32 + 8 * g + 4 * h] = vv;
    }
}

// ---------------------------------------------------------------------------
// Launcher. Workspace ~106 MB:
//  Wqh,Wql,Wkh,Wkl,Wvh 5x2MB @0; Xf @10M; Qh @26M; Ql @42M; Kh @58M;
//  Kl @74M; Vt @90M
// ---------------------------------------------------------------------------
extern "C" void kernel_launch(void* const* d_in, const int* in_sizes, int n_in,
                              void* d_out, int out_size, void* d_ws, size_t ws_size,
                              hipStream_t stream) {
  const float* X  = (const float*)d_in[0];
  const float* Wq = (const float*)d_in[1];
  const float* Wk = (const float*)d_in[2];
  const float* Wv = (const float*)d_in[3];
  float* out = (float*)d_out;
  char* ws = (char*)d_ws;

  const size_t WSZ = (size_t)E_ * E_ * sizeof(f16);   // 2 MB
  const size_t QSZ = (size_t)M_ * E_ * sizeof(f16);   // 16 MB
  f16* Wqh = (f16*)(ws);
  f16* Wql = (f16*)(ws + WSZ);
  f16* Wkh = (f16*)(ws + 2 * WSZ);
  f16* Wkl = (f16*)(ws + 3 * WSZ);
  f16* Wvh = (f16*)(ws + 4 * WSZ);
  char* p = ws + 5 * WSZ;
  f16* Xf = (f16*)(p);
  f16* Qh = (f16*)(p + QSZ);
  f16* Ql = (f16*)(p + 2 * QSZ);
  f16* Kh = (f16*)(p + 3 * QSZ);
  f16* Kl = (f16*)(p + 4 * QSZ);
  f16* Vt = (f16*)(p + 5 * QSZ);

  presplit_kernel<<<4096, 256, 0, stream>>>(X, Xf);
  wt_conv3_kernel<<<dim3(16, 16, 3), dim3(64, 8), 0, stream>>>(
      Wq, Wk, Wv, Wqh, Wql, Wkh, Wkl, Wvh);

  gemm_qkv_kernel<<<dim3(8, 64, 3), 256, 0, stream>>>(
      Xf, Wqh, Wql, Wkh, Wkl, Wvh, Qh, Ql, Kh, Kl, Vt);

  attn_kernel<<<1024, 256, 0, stream>>>(Qh, Ql, Kh, Kl, Vt, out);
}

// Round 6
// 160.609 us; speedup vs baseline: 4.3531x; 1.2186x over previous
//
#include <hip/hip_runtime.h>
#include <cstdint>
#include <cstddef>

#define B_ 8
#define S_ 1024
#define E_ 1024
#define H_ 16
#define D_ 64
#define M_ (B_*S_)

typedef _Float16 f16;
typedef __attribute__((ext_vector_type(8))) _Float16 f16x8;
typedef __attribute__((ext_vector_type(4))) _Float16 f16x4;
typedef __attribute__((ext_vector_type(4))) float  f32x4;
typedef __attribute__((ext_vector_type(16))) float f32x16;
typedef __attribute__((ext_vector_type(4))) int    int4v;
typedef __attribute__((ext_vector_type(2))) int    int2v;

__device__ __forceinline__ f32x4 mfma16(f16x8 a, f16x8 b, f32x4 c) {
  return __builtin_amdgcn_mfma_f32_16x16x32_f16(a, b, c, 0, 0, 0);
}
__device__ __forceinline__ f32x16 mfma32(f16x8 a, f16x8 b, f32x16 c) {
  return __builtin_amdgcn_mfma_f32_32x32x16_f16(a, b, c, 0, 0, 0);
}
__device__ __forceinline__ void gll16(const f16* g, f16* l) {
  __builtin_amdgcn_global_load_lds(
      (const __attribute__((address_space(1))) void*)g,
      (__attribute__((address_space(3))) void*)l, 16, 0, 0);
}
__device__ __forceinline__ int pkrtz(float lo, float hi) {
  return __builtin_bit_cast(int, __builtin_amdgcn_cvt_pkrtz(lo, hi));
}

// ---------------------------------------------------------------------------
// X fp32 -> fp16 (single)
// ---------------------------------------------------------------------------
__global__ __launch_bounds__(256) void presplit_kernel(
    const float* __restrict__ X, f16* __restrict__ Xf) {
  size_t i = ((size_t)blockIdx.x * 256 + threadIdx.x) * 8;
  f32x4 v0 = *(const f32x4*)&X[i];
  f32x4 v1 = *(const f32x4*)&X[i + 4];
  f16x8 hv;
#pragma unroll
  for (int j = 0; j < 4; ++j) {
    hv[j] = (f16)v0[j];
    hv[j + 4] = (f16)v1[j];
  }
  *(f16x8*)&Xf[i] = hv;
}

// ---------------------------------------------------------------------------
// Transpose + convert weights -> single fp16, [f][e] layout.
// W_Q pre-scaled by log2(e) (softmax runs in exp2 domain).
// Single-fp16 W adds only ~7e-3 sigma to scores (vs ~0.17 threshold):
// the precision-critical split is Q/K STORAGE (GEMM epilogue), not W.
// ---------------------------------------------------------------------------
__global__ __launch_bounds__(512) void wt_conv3_kernel(
    const float* __restrict__ Wq, const float* __restrict__ Wk,
    const float* __restrict__ Wv, f16* __restrict__ oq, f16* __restrict__ ok,
    f16* __restrict__ ov) {
  const float* W = blockIdx.z == 0 ? Wq : (blockIdx.z == 1 ? Wk : Wv);
  f16* o = blockIdx.z == 0 ? oq : (blockIdx.z == 1 ? ok : ov);
  const float scl = blockIdx.z == 0 ? 1.4426950408889634f : 1.0f;
  __shared__ float t[64][65];
  const int f0 = blockIdx.x * 64, e0 = blockIdx.y * 64;
  const int tx = threadIdx.x, ty = threadIdx.y;
#pragma unroll
  for (int j = 0; j < 8; ++j)
    t[ty + 8 * j][tx] = W[(size_t)(e0 + ty + 8 * j) * E_ + f0 + tx];
  __syncthreads();
#pragma unroll
  for (int j = 0; j < 8; ++j)
    o[(size_t)(f0 + ty + 8 * j) * E_ + e0 + tx] =
        (f16)(t[tx][ty + 8 * j] * scl);
}

// ---------------------------------------------------------------------------
// Fused single-term QKV GEMM: O = X(f16) * W(f16), N = 3072 logical.
// Grid 1536 linear; XCD-chunked swizzle: each XCD owns 8 m-panels x all 24
// n-blocks so the X panel is fetched once per XCD (round-5: 202MB fetch from
// cross-XCD spreading).  n-block z: 0-7=Q (hi/lo out), 8-15=K (hi/lo out),
// 16-23=V (transposed single out).
// BM=BN=128, BK=64, 4 waves, LDS 32KB -> 4 blocks/CU.  XOR-swizzled LDS via
// pre-swizzled global source (rule 21).
// ---------------------------------------------------------------------------
__global__ __launch_bounds__(256) void gemm_qkv_kernel(
    const f16* __restrict__ Xf,
    const f16* __restrict__ Wq, const f16* __restrict__ Wk,
    const f16* __restrict__ Wv,
    f16* __restrict__ Qh, f16* __restrict__ Ql,
    f16* __restrict__ Kh, f16* __restrict__ Kl, f16* __restrict__ Vt) {
  __shared__ f16 sA[128][64], sB[128][64];   // 32 KB
  const int bid = blockIdx.x;
  const int xcd = bid & 7, idx = bid >> 3;   // idx in [0,192)
  const int mb = xcd * 8 + idx / 24;         // [0,64)
  const int nb = idx % 24;
  const int z = nb >> 3;
  const int n0 = (nb & 7) * 128, m0 = mb * 128;
  const f16* __restrict__ Bt = z == 0 ? Wq : (z == 1 ? Wk : Wv);
  const int tid = threadIdx.x;
  const int lane = tid & 63, w = tid >> 6;
  const int wm = (w >> 1) * 64, wn = (w & 1) * 64;
  const int fr = lane & 15, fg = lane >> 4;
  f32x4 acc[4][4] = {};
  for (int k0 = 0; k0 < E_; k0 += 64) {
#pragma unroll
    for (int i = 0; i < 4; ++i) {
      int ci = tid + i * 256;
      int r = ci >> 3, cl = ci & 7;
      int cs = (cl ^ (r & 7)) * 8;       // pre-swizzled global source column
      gll16(Xf + (size_t)(m0 + r) * E_ + k0 + cs, &sA[0][0] + ci * 8);
      gll16(Bt + (size_t)(n0 + r) * E_ + k0 + cs, &sB[0][0] + ci * 8);
    }
    __syncthreads();   // drains vmcnt -> staged tile visible to all
#pragma unroll
    for (int kh2 = 0; kh2 < 2; ++kh2) {   // two 32-wide MFMA K-steps
      f16x8 ah[4];
#pragma unroll
      for (int mi = 0; mi < 4; ++mi) {
        int rA = wm + mi * 16 + fr;
        ah[mi] = *(const f16x8*)&sA[rA][(((kh2 * 4 + fg) ^ (rA & 7))) * 8];
      }
#pragma unroll
      for (int ni = 0; ni < 4; ++ni) {
        int rB = wn + ni * 16 + fr;
        f16x8 bh = *(const f16x8*)&sB[rB][(((kh2 * 4 + fg) ^ (rB & 7))) * 8];
#pragma unroll
        for (int mi = 0; mi < 4; ++mi)
          acc[mi][ni] = mfma16(ah[mi], bh, acc[mi][ni]);
      }
    }
    __syncthreads();   // compute done before next stage overwrites
  }
  if (z < 2) {
    f16* Oh = z == 0 ? Qh : Kh;
    f16* Ol = z == 0 ? Ql : Kl;
#pragma unroll
    for (int mi = 0; mi < 4; ++mi)
#pragma unroll
      for (int ni = 0; ni < 4; ++ni)
#pragma unroll
        for (int r = 0; r < 4; ++r) {
          int row = m0 + wm + mi * 16 + (lane >> 4) * 4 + r;
          int col = n0 + wn + ni * 16 + fr;
          float v = acc[mi][ni][r];
          int bb = row >> 10, s = row & 1023;
          int hd = col >> 6, d = col & 63;
          size_t idx2 = ((size_t)(bb * H_ + hd) * S_ + s) * D_ + d;
          f16 hh = (f16)v;
          Oh[idx2] = hh;
          Ol[idx2] = (f16)(v - (float)hh);
        }
  } else {
#pragma unroll
    for (int mi = 0; mi < 4; ++mi)
#pragma unroll
      for (int ni = 0; ni < 4; ++ni) {
        int row = m0 + wm + mi * 16 + (lane >> 4) * 4;
        int col = n0 + wn + ni * 16 + fr;
        int bb = row >> 10, s = row & 1023;
        int hd = col >> 6, d = col & 63;
        f16x4 p;
#pragma unroll
        for (int r = 0; r < 4; ++r) p[r] = (f16)acc[mi][ni][r];
        *(f16x4*)&Vt[((size_t)(bb * H_ + hd) * D_ + d) * S_ + s] = p;
      }
  }
}

// ---------------------------------------------------------------------------
// Flash attention + ReLU.  Grid 512 = exactly 2 blocks/CU, no tail.
// 4 waves x 64 q (qf=2): K/V LDS reads + staging amortized over 2x queries
// (round-5 budget: LDS-read cycles > MFMA cycles at qf=1).
// Per-qf softmax->PV keeps register peak ~230 (sc freed per qf; V re-read).
// 3-term fp16 QK^T (storage-split Q/K); exp2 domain; defer-max THR=11;
// in-register P via pkrtz+permlane32_swap; double-buffered gll staging.
// ---------------------------------------------------------------------------
__global__ __launch_bounds__(256, 2) void attn_kernel(
    const f16* __restrict__ Qh, const f16* __restrict__ Ql,
    const f16* __restrict__ Kh, const f16* __restrict__ Kl,
    const f16* __restrict__ Vt, float* __restrict__ out) {
  __shared__ f16 sKh[2][64][64], sKl[2][64][64], sV[2][64][64];
  const int bid = blockIdx.x;
  const int idx = bid >> 3;                       // [0,64)
  const int bh = (bid & 7) * 16 + (idx >> 2);     // same XCD: 16 heads chunk
  const int qb = idx & 3;                         // 4 q-blocks, adjacent bids
  const int hd = bh & 15, bb = bh >> 4;
  const int tid = threadIdx.x;
  const int lane = tid & 63, w = tid >> 6;
  const int cq = lane & 31, h = lane >> 5;
  const size_t base = (size_t)bh * (S_ * D_);
  const f16* Qh_p = Qh + base;
  const f16* Ql_p = Ql + base;
  const f16* Kh_p = Kh + base;
  const f16* Kl_p = Kl + base;
  const f16* Vt_p = Vt + base;
  const int q0 = qb * 256 + w * 64;

  f16x8 qh_[2][4], ql_[2][4];
#pragma unroll
  for (int qf = 0; qf < 2; ++qf)
#pragma unroll
    for (int ks = 0; ks < 4; ++ks) {
      size_t off = (size_t)(q0 + qf * 32 + cq) * D_ + ks * 16 + 8 * h;
      qh_[qf][ks] = *(const f16x8*)&Qh_p[off];
      ql_[qf][ks] = *(const f16x8*)&Ql_p[off];
    }

  float m_run[2] = {-1e30f, -1e30f};
  float l_run[2] = {0.f, 0.f};
  f32x16 O[2][2] = {};

#define STAGE(buf, kb)                                                        \
  {                                                                           \
    _Pragma("unroll")                                                         \
    for (int half = 0; half < 2; ++half) {                                    \
      int ci = tid + half * 256;                                              \
      int row = ci >> 3, cl = ci & 7;                                         \
      int cs = cl ^ (row & 7);                                                \
      gll16(Kh_p + (size_t)((kb) + row) * D_ + cs * 8, &sKh[buf][0][0] + ci * 8); \
      gll16(Kl_p + (size_t)((kb) + row) * D_ + cs * 8, &sKl[buf][0][0] + ci * 8); \
      gll16(Vt_p + (size_t)row * S_ + (kb) + cs * 8, &sV[buf][0][0] + ci * 8);    \
    }                                                                         \
  }

  STAGE(0, 0);
  int cur = 0;
  for (int t = 0; t < 16; ++t) {
    __builtin_amdgcn_s_barrier();          // all waves done with buf cur^1
    if (t < 15) {
      STAGE(cur ^ 1, (t + 1) * 64);
      asm volatile("s_waitcnt vmcnt(6)" ::: "memory");
    } else {
      asm volatile("s_waitcnt vmcnt(0)" ::: "memory");
    }
    __builtin_amdgcn_sched_barrier(0);
    __builtin_amdgcn_s_barrier();          // staged chunk visible to all

    // ---- QK^T (swapped, 3-term, both qf share K fragments)
    f32x16 sc[2][2] = {};
    __builtin_amdgcn_s_setprio(1);
#pragma unroll
    for (int f = 0; f < 2; ++f)
#pragma unroll
      for (int ks = 0; ks < 4; ++ks) {
        int row = f * 32 + cq;
        int cc = ((2 * ks + h) ^ (cq & 7)) * 8;
        f16x8 kh = *(const f16x8*)&sKh[cur][row][cc];
        f16x8 kl = *(const f16x8*)&sKl[cur][row][cc];
#pragma unroll
        for (int qf = 0; qf < 2; ++qf) {
          sc[qf][f] = mfma32(kh, qh_[qf][ks], sc[qf][f]);
          sc[qf][f] = mfma32(kl, qh_[qf][ks], sc[qf][f]);
          sc[qf][f] = mfma32(kh, ql_[qf][ks], sc[qf][f]);
        }
      }
    __builtin_amdgcn_s_setprio(0);

    // ---- per qf: softmax (exp2 domain) -> P frags -> PV
#pragma unroll
    for (int qf = 0; qf < 2; ++qf) {
      float t8[8];
#pragma unroll
      for (int i = 0; i < 8; ++i)
        t8[i] = fmaxf(fmaxf(sc[qf][0][i], sc[qf][0][i + 8]),
                      fmaxf(sc[qf][1][i], sc[qf][1][i + 8]));
      float pmax = fmaxf(fmaxf(fmaxf(t8[0], t8[4]), fmaxf(t8[1], t8[5])),
                         fmaxf(fmaxf(t8[2], t8[6]), fmaxf(t8[3], t8[7])));
      pmax = fmaxf(pmax, __shfl_xor(pmax, 32));
      if (__any(pmax > m_run[qf] + 11.0f)) {
        float mn = fmaxf(m_run[qf], pmax);
        float scale = __builtin_amdgcn_exp2f(m_run[qf] - mn);
        m_run[qf] = mn;
        l_run[qf] *= scale;
#pragma unroll
        for (int df = 0; df < 2; ++df)
#pragma unroll
          for (int i = 0; i < 16; ++i) O[qf][df][i] *= scale;
      }
      float rs0 = 0.f, rs1 = 0.f, rs2 = 0.f, rs3 = 0.f;
#pragma unroll
      for (int f = 0; f < 2; ++f)
#pragma unroll
        for (int r = 0; r < 16; ++r) {
          float p = __builtin_amdgcn_exp2f(sc[qf][f][r] - m_run[qf]);
          if ((r & 3) == 0) rs0 += p;
          else if ((r & 3) == 1) rs1 += p;
          else if ((r & 3) == 2) rs2 += p;
          else rs3 += p;
          sc[qf][f][r] = p;
        }
      float rs = (rs0 + rs1) + (rs2 + rs3);
      rs += __shfl_xor(rs, 32);
      l_run[qf] += rs;

      // P fragments in-register: pf[ks][j] = P[16ks+8h+j][cq]
      f16x8 pf[4];
#pragma unroll
      for (int f = 0; f < 2; ++f)
#pragma unroll
        for (int ksl = 0; ksl < 2; ++ksl) {
          int b0 = 8 * ksl;
          int a1 = pkrtz(sc[qf][f][b0 + 0], sc[qf][f][b0 + 1]);
          int b1 = pkrtz(sc[qf][f][b0 + 4], sc[qf][f][b0 + 5]);
          int2v r1 = __builtin_amdgcn_permlane32_swap(a1, b1, false, false);
          int a2 = pkrtz(sc[qf][f][b0 + 2], sc[qf][f][b0 + 3]);
          int b2 = pkrtz(sc[qf][f][b0 + 6], sc[qf][f][b0 + 7]);
          int2v r2 = __builtin_amdgcn_permlane32_swap(a2, b2, false, false);
          int4v wd;
          wd[0] = r1[0]; wd[1] = r2[0]; wd[2] = r1[1]; wd[3] = r2[1];
          pf[2 * f + ksl] = __builtin_bit_cast(f16x8, wd);
        }

      // PV: O[qf][d][q] += V^T[d][k] * P[k][q]  (V frags re-read per qf)
      __builtin_amdgcn_s_setprio(1);
#pragma unroll
      for (int ks = 0; ks < 4; ++ks) {
        int cc = ((2 * ks + h) ^ (cq & 7)) * 8;
#pragma unroll
        for (int df = 0; df < 2; ++df) {
          f16x8 vf = *(const f16x8*)&sV[cur][df * 32 + cq][cc];
          O[qf][df] = mfma32(vf, pf[ks], O[qf][df]);
        }
      }
      __builtin_amdgcn_s_setprio(0);
    }
    cur ^= 1;
  }

  // ---- epilogue: relu(O/l) -> fp32 [B,S,E]
#pragma unroll
  for (int qf = 0; qf < 2; ++qf) {
    float inv = 1.0f / l_run[qf];
    int s = q0 + qf * 32 + cq;
    float* orow = out + ((size_t)bb * S_ + s) * E_ + hd * 64;
#pragma unroll
    for (int df = 0; df < 2; ++df)
#pragma unroll
      for (int g = 0; g < 4; ++g) {
        f32x4 vv;
#pragma unroll
        for (int j = 0; j < 4; ++j)
          vv[j] = fmaxf(O[qf][df][4 * g + j] * inv, 0.f);
        *(f32x4*)&orow[df * 32 + 8 * g + 4 * h] = vv;
      }
  }
}

// ---------------------------------------------------------------------------
// Launcher. Workspace ~102 MB:
//  Wq,Wk,Wv 3x2MB @0; Xf @6M; Qh @22M; Ql @38M; Kh @54M; Kl @70M; Vt @86M
// ---------------------------------------------------------------------------
extern "C" void kernel_launch(void* const* d_in, const int* in_sizes, int n_in,
                              void* d_out, int out_size, void* d_ws, size_t ws_size,
                              hipStream_t stream) {
  const float* X  = (const float*)d_in[0];
  const float* Wq = (const float*)d_in[1];
  const float* Wk = (const float*)d_in[2];
  const float* Wv = (const float*)d_in[3];
  float* out = (float*)d_out;
  char* ws = (char*)d_ws;

  const size_t WSZ = (size_t)E_ * E_ * sizeof(f16);   // 2 MB
  const size_t QSZ = (size_t)M_ * E_ * sizeof(f16);   // 16 MB
  f16* Wqf = (f16*)(ws);
  f16* Wkf = (f16*)(ws + WSZ);
  f16* Wvf = (f16*)(ws + 2 * WSZ);
  char* p = ws + 3 * WSZ;
  f16* Xf = (f16*)(p);
  f16* Qh = (f16*)(p + QSZ);
  f16* Ql = (f16*)(p + 2 * QSZ);
  f16* Kh = (f16*)(p + 3 * QSZ);
  f16* Kl = (f16*)(p + 4 * QSZ);
  f16* Vt = (f16*)(p + 5 * QSZ);

  presplit_kernel<<<4096, 256, 0, stream>>>(X, Xf);
  wt_conv3_kernel<<<dim3(16, 16, 3), dim3(64, 8), 0, stream>>>(
      Wq, Wk, Wv, Wqf, Wkf, Wvf);

  gemm_qkv_kernel<<<1536, 256, 0, stream>>>(
      Xf, Wqf, Wkf, Wvf, Qh, Ql, Kh, Kl, Vt);

  attn_kernel<<<512, 256, 0, stream>>>(Qh, Ql, Kh, Kl, Vt, out);
}